// Round 18
// baseline (288.982 us; speedup 1.0000x reference)
//
#include <hip/hip_runtime.h>
#include <hip/hip_bf16.h>
#include <hip/hip_fp16.h>

#define NNODES 50000
#define NEDGES 800000
#define FDIM   128
#define NHEADS 4
#define NSCANB ((NNODES + 1023) / 1024)   // 49
#define NBLK   782                        // ceil(50000/64)
#define NT16   (NBLK * 4)                 // 16-row tiles incl. pad = 3128
#define NFULL  3125                       // 50000/16 exactly

typedef __attribute__((ext_vector_type(8))) short  bf16x8;
typedef __attribute__((ext_vector_type(4))) float  f32x4;
typedef _Float16 h2f __attribute__((ext_vector_type(2)));

static __device__ __forceinline__ unsigned short f2bf(float f) {
    __hip_bfloat16 h = __float2bfloat16(f);
    return *reinterpret_cast<unsigned short*>(&h);
}
static __device__ __forceinline__ unsigned short f2h(float f) {
    __half h = __float2half(f);
    return *reinterpret_cast<unsigned short*>(&h);
}
static __device__ __forceinline__ h2f u2h2(unsigned int u) {
    return *reinterpret_cast<h2f*>(&u);
}
static __device__ __forceinline__ float hdot4(h2f a01, h2f a23, h2f b01, h2f b23) {
#if __has_builtin(__builtin_amdgcn_fdot2)
    return __builtin_amdgcn_fdot2(a01, b01,
           __builtin_amdgcn_fdot2(a23, b23, 0.0f, false), false);
#else
    return (float)a01[0]*(float)b01[0] + (float)a01[1]*(float)b01[1]
         + (float)a23[0]*(float)b23[0] + (float)a23[1]*(float)b23[1];
#endif
}

// ---------------------------------------------------------------------------
// prep: blocks 0..31 -> weights to fragment-ordered bf16; blocks 32.. -> deg=0
// ---------------------------------------------------------------------------
__global__ __launch_bounds__(256) void tgd_prep(
    const float* __restrict__ Wq, const float* __restrict__ Wk,
    const float* __restrict__ Wv, const float* __restrict__ Wsk,
    unsigned short* __restrict__ Wt2, int* __restrict__ deg)
{
    const int b = blockIdx.x;
    if (b < 32) {
        int t = b * 256 + threadIdx.x;   // 0..8191
        int m    = t >> 11;
        int ct   = (t >> 8) & 7;
        int ks   = (t >> 6) & 3;
        int lane = t & 63;
        int c  = ct * 16 + (lane & 15);
        int k0 = ks * 32 + (lane >> 4) * 8;
        const float* W = (m == 0) ? Wq : (m == 1) ? Wk : (m == 2) ? Wv : Wsk;
        unsigned short u[8];
        #pragma unroll
        for (int j = 0; j < 8; ++j)
            u[j] = f2bf(W[(size_t)(k0 + j) * FDIM + c]);
        *reinterpret_cast<uint4*>(&Wt2[(size_t)t * 8]) = *reinterpret_cast<uint4*>(u);
    } else {
        int i0 = ((b - 32) * 256 + threadIdx.x) * 4;
        #pragma unroll
        for (int j = 0; j < 4; ++j)
            if (i0 + j < NNODES) deg[i0 + j] = 0;
    }
}

// ---------------------------------------------------------------------------
// cvt_xa: x -> A-fragment-ordered bf16 via LDS staging (coalesced 8KB reads).
// Tail: one edge histogram increment per thread (800,768 threads >= E).
// ---------------------------------------------------------------------------
__global__ __launch_bounds__(256) void tgd_cvt_xa(const float* __restrict__ x,
                                                  unsigned short* __restrict__ xa,
                                                  const int* __restrict__ ei,
                                                  int* __restrict__ deg)
{
    __shared__ unsigned short lds[16 * 136];
    const int gt  = blockIdx.x;
    const int tid = threadIdx.x;

    if (gt < NFULL) {
        const float* src = x + (size_t)gt * 2048 + tid * 8;
        float4 f0 = *reinterpret_cast<const float4*>(src);
        float4 f1 = *reinterpret_cast<const float4*>(src + 4);
        const int row = tid >> 4;
        const int col = (tid & 15) * 8;
        unsigned short* d = &lds[row * 136 + col];
        d[0]=f2bf(f0.x); d[1]=f2bf(f0.y); d[2]=f2bf(f0.z); d[3]=f2bf(f0.w);
        d[4]=f2bf(f1.x); d[5]=f2bf(f1.y); d[6]=f2bf(f1.z); d[7]=f2bf(f1.w);
    }
    __syncthreads();

    const int lane = tid & 63;
    const int ks   = tid >> 6;
    const int row  = lane & 15;
    const int k0   = ks * 32 + (lane >> 4) * 8;
    unsigned short u[8];
    if (gt < NFULL) {
        #pragma unroll
        for (int j = 0; j < 8; ++j) u[j] = lds[row * 136 + k0 + j];
    } else {
        #pragma unroll
        for (int j = 0; j < 8; ++j) u[j] = 0;
    }
    *reinterpret_cast<uint4*>(&xa[((size_t)gt * 256 + tid) * 8]) =
        *reinterpret_cast<uint4*>(u);

    // hist tail: 1 edge per thread
    int e = gt * 256 + tid;
    if (e < NEDGES) atomicAdd(&deg[ei[NEDGES + e]], 1);
}

// ---------------------------------------------------------------------------
// MFMA GEMM (r16 structure): A from fragment-ordered xa, B from Wt2.
// LDS-staged coalesced epilogue; q,k,v stored as f16.
// ---------------------------------------------------------------------------
__global__ __launch_bounds__(512) void tgd_gemm_mfma(
    const unsigned short* __restrict__ xa, const unsigned short* __restrict__ Wt2,
    const float* __restrict__ bq, const float* __restrict__ bk,
    const float* __restrict__ bv, const float* __restrict__ bsk,
    unsigned short* __restrict__ qb, unsigned short* __restrict__ kv,
    float* __restrict__ outp)
{
    __shared__ float st[64 * 128];                      // 32KB staging
    unsigned short* sth = (unsigned short*)st;

    const int tid  = threadIdx.x;
    const int wave = tid >> 6, lane = tid & 63;
    const int mp   = wave >> 2;           // 0: (q,k)  1: (v,skip)
    const int wr   = wave & 3;
    const int l16  = lane & 15, lhi = lane >> 4;
    const int gt   = blockIdx.x * 4 + wr;
    const int base = blockIdx.x * 64;

    bf16x8 a[4];
    #pragma unroll
    for (int ks = 0; ks < 4; ++ks)
        a[ks] = *reinterpret_cast<const bf16x8*>(
            xa + ((size_t)(gt * 4 + ks) * 64 + lane) * 8);

    f32x4 acc[2][8];
    #pragma unroll
    for (int m2 = 0; m2 < 2; ++m2)
        #pragma unroll
        for (int ct = 0; ct < 8; ++ct)
            acc[m2][ct] = (f32x4){0.f, 0.f, 0.f, 0.f};

    #pragma unroll
    for (int ks = 0; ks < 4; ++ks) {
        #pragma unroll
        for (int m2 = 0; m2 < 2; ++m2) {
            const int m = mp * 2 + m2;
            const unsigned short* wb =
                Wt2 + ((size_t)((m * 8 * 4 + ks) * 64) + lane) * 8;
            #pragma unroll
            for (int ct = 0; ct < 8; ++ct) {
                bf16x8 b = *reinterpret_cast<const bf16x8*>(wb + (size_t)ct * 2048);
                acc[m2][ct] = __builtin_amdgcn_mfma_f32_16x16x32_bf16(
                    a[ks], b, acc[m2][ct], 0, 0, 0);
            }
        }
    }

    const int rowl0 = wr * 16 + lhi * 4;

    // ---- phase 1: q -> qb (f16) ----
    if (mp == 0) {
        #pragma unroll
        for (int ct = 0; ct < 8; ++ct) {
            int col = ct * 16 + l16;
            float bval = bq[col];
            #pragma unroll
            for (int r = 0; r < 4; ++r)
                sth[(rowl0 + r) * 128 + col] = f2h(acc[0][ct][r] + bval);
        }
    }
    __syncthreads();
    #pragma unroll
    for (int i = 0; i < 2; ++i) {
        int idx = i * 512 + tid;           // uint4 idx in [64][16]
        int row = idx >> 4, c8 = idx & 15;
        if (base + row < NNODES)
            *reinterpret_cast<uint4*>(&qb[(size_t)(base + row) * 128 + c8 * 8]) =
                *reinterpret_cast<const uint4*>(&sth[row * 128 + c8 * 8]);
    }
    __syncthreads();

    // ---- phase 2: skip -> outp (fp32) ----
    if (mp == 1) {
        #pragma unroll
        for (int ct = 0; ct < 8; ++ct) {
            int col = ct * 16 + l16;
            float bval = bsk[col];
            #pragma unroll
            for (int r = 0; r < 4; ++r)
                st[(rowl0 + r) * 128 + col] = acc[1][ct][r] + bval;
        }
    }
    __syncthreads();
    #pragma unroll
    for (int i = 0; i < 4; ++i) {
        int idx = i * 512 + tid;
        int row = idx >> 5, c4 = idx & 31;
        if (base + row < NNODES)
            *reinterpret_cast<float4*>(&outp[(size_t)(base + row) * FDIM + c4 * 4]) =
                *reinterpret_cast<const float4*>(&st[row * 128 + c4 * 4]);
    }
    __syncthreads();

    // ---- phase 3: k | v -> kv f16 [64][256] ----
    {
        const int off  = (mp == 0) ? 0 : 128;
        const int m2s  = (mp == 0) ? 1 : 0;
        const float* bias = (mp == 0) ? bk : bv;
        #pragma unroll
        for (int ct = 0; ct < 8; ++ct) {
            int col = ct * 16 + l16;
            float bval = bias[col];
            #pragma unroll
            for (int r = 0; r < 4; ++r)
                sth[(rowl0 + r) * 256 + off + col] = f2h(acc[m2s][ct][r] + bval);
        }
    }
    __syncthreads();
    #pragma unroll
    for (int i = 0; i < 4; ++i) {
        int idx = i * 512 + tid;
        int row = idx >> 5, c8 = idx & 31;
        if (base + row < NNODES)
            *reinterpret_cast<uint4*>(&kv[(size_t)(base + row) * 256 + c8 * 8]) =
                *reinterpret_cast<const uint4*>(&sth[row * 256 + c8 * 8]);
    }
}

// ---------------------------------------------------------------------------
// scan1: local inclusive scan per 1024-block; block total -> bsum
// ---------------------------------------------------------------------------
__global__ __launch_bounds__(1024) void tgd_scan1(const int* __restrict__ deg,
                                                  int* __restrict__ rowptr,
                                                  int* __restrict__ bsum)
{
    __shared__ int buf[1024];
    const int tid = threadIdx.x;
    const int i   = blockIdx.x * 1024 + tid;
    int d = (i < NNODES) ? deg[i] : 0;
    buf[tid] = d;
    __syncthreads();
    #pragma unroll
    for (int off = 1; off < 1024; off <<= 1) {
        int t2 = (tid >= off) ? buf[tid - off] : 0;
        __syncthreads();
        buf[tid] += t2;
        __syncthreads();
    }
    if (i < NNODES) rowptr[i + 1] = buf[tid];
    if (tid == 1023) bsum[blockIdx.x] = buf[1023];
}

// ---------------------------------------------------------------------------
// scan3 (scan2 folded): each block wave-reduces its prefix of bsum.
// ---------------------------------------------------------------------------
__global__ __launch_bounds__(1024) void tgd_scan3(const int* __restrict__ deg,
                                                  const int* __restrict__ bsum,
                                                  int* __restrict__ rowptr,
                                                  int* __restrict__ ofs)
{
    __shared__ int sboff;
    const int tid = threadIdx.x;
    if (tid < 64) {
        int v = (tid < blockIdx.x) ? bsum[tid] : 0;   // blockIdx.x <= 48
        #pragma unroll
        for (int m = 32; m >= 1; m >>= 1) v += __shfl_xor(v, m);
        if (tid == 0) sboff = v;
    }
    __syncthreads();
    const int i = blockIdx.x * 1024 + tid;
    if (i < NNODES) {
        int r = rowptr[i + 1] + sboff;
        rowptr[i + 1] = r;
        ofs[i] = r - deg[i];
    }
    if (i == 0) rowptr[0] = 0;
}

__global__ __launch_bounds__(256) void tgd_build(const int* __restrict__ ei,
                                                 int* __restrict__ ofs,
                                                 int* __restrict__ csr)
{
    int t = blockIdx.x * 256 + threadIdx.x;
    if (t >= NEDGES) return;
    int src = ei[t];
    int dst = ei[NEDGES + t];
    int pos = atomicAdd(&ofs[dst], 1);
    csr[pos] = src;
}

// ---------------------------------------------------------------------------
// Fused per-dst aggregation: 1 wave per node, unroll-4, f16 + v_dot2.
// Lane l loads 4 halves at kv[src*256+4l]: lanes 0..31 k, 32..63 v.
// ---------------------------------------------------------------------------
__global__ __launch_bounds__(256) void tgd_agg(
    const int* __restrict__ csr, const int* __restrict__ rowptr,
    const unsigned short* __restrict__ qb, const unsigned short* __restrict__ kv,
    float* __restrict__ outp)
{
    const int node = blockIdx.x * 4 + (threadIdx.x >> 6);
    const int lane = threadIdx.x & 63;
    if (node >= NNODES) return;
    const int start = rowptr[node];
    const int end   = rowptr[node + 1];
    if (start == end) return;

    const bool isK = (lane < 32);
    h2f q01 = (h2f)(_Float16)0, q23 = (h2f)(_Float16)0;
    if (isK) {
        uint2 qu = *reinterpret_cast<const uint2*>(&qb[(size_t)node * FDIM + lane * 4]);
        q01 = u2h2(qu.x); q23 = u2h2(qu.y);
    }
    const float inv = 0.17677669529663687f;  // 1/sqrt(32)

    float  den = 0.0f;
    float4 acc = {0.f, 0.f, 0.f, 0.f};

    for (int base = start; base < end; base += 64) {
        const int cnt = min(64, end - base);
        int myid = (lane < cnt) ? csr[base + lane] : 0;

        int j = 0;
        for (; j + 3 < cnt; j += 4) {
            int s0 = __shfl(myid, j);
            int s1 = __shfl(myid, j + 1);
            int s2 = __shfl(myid, j + 2);
            int s3 = __shfl(myid, j + 3);
            uint2 r0 = *reinterpret_cast<const uint2*>(&kv[(size_t)s0 * 256 + lane * 4]);
            uint2 r1 = *reinterpret_cast<const uint2*>(&kv[(size_t)s1 * 256 + lane * 4]);
            uint2 r2 = *reinterpret_cast<const uint2*>(&kv[(size_t)s2 * 256 + lane * 4]);
            uint2 r3 = *reinterpret_cast<const uint2*>(&kv[(size_t)s3 * 256 + lane * 4]);

            h2f a01 = u2h2(r0.x), a23 = u2h2(r0.y);
            h2f b01 = u2h2(r1.x), b23 = u2h2(r1.y);
            h2f c01 = u2h2(r2.x), c23 = u2h2(r2.y);
            h2f d01 = u2h2(r3.x), d23 = u2h2(r3.y);

            float sA = hdot4(q01, q23, a01, a23);
            float sB = hdot4(q01, q23, b01, b23);
            float sC = hdot4(q01, q23, c01, c23);
            float sD = hdot4(q01, q23, d01, d23);
            sA += __shfl_xor(sA, 1);  sB += __shfl_xor(sB, 1);
            sC += __shfl_xor(sC, 1);  sD += __shfl_xor(sD, 1);
            sA += __shfl_xor(sA, 2);  sB += __shfl_xor(sB, 2);
            sC += __shfl_xor(sC, 2);  sD += __shfl_xor(sD, 2);
            sA += __shfl_xor(sA, 4);  sB += __shfl_xor(sB, 4);
            sC += __shfl_xor(sC, 4);  sD += __shfl_xor(sD, 4);
            float wA = __expf(sA * inv);
            float wB = __expf(sB * inv);
            float wC = __expf(sC * inv);
            float wD = __expf(sD * inv);
            wA = __shfl_xor(wA, 32);
            wB = __shfl_xor(wB, 32);
            wC = __shfl_xor(wC, 32);
            wD = __shfl_xor(wD, 32);
            if (!isK) {
                den += (wA + wB) + (wC + wD);
                acc.x += wA*(float)a01[0] + wB*(float)b01[0] + wC*(float)c01[0] + wD*(float)d01[0];
                acc.y += wA*(float)a01[1] + wB*(float)b01[1] + wC*(float)c01[1] + wD*(float)d01[1];
                acc.z += wA*(float)a23[0] + wB*(float)b23[0] + wC*(float)c23[0] + wD*(float)d23[0];
                acc.w += wA*(float)a23[1] + wB*(float)b23[1] + wC*(float)c23[1] + wD*(float)d23[1];
            }
        }
        for (; j < cnt; ++j) {
            int s0 = __shfl(myid, j);
            uint2 r0 = *reinterpret_cast<const uint2*>(&kv[(size_t)s0 * 256 + lane * 4]);
            h2f a01 = u2h2(r0.x), a23 = u2h2(r0.y);
            float sA = hdot4(q01, q23, a01, a23);
            sA += __shfl_xor(sA, 1);
            sA += __shfl_xor(sA, 2);
            sA += __shfl_xor(sA, 4);
            float wA = __expf(sA * inv);
            wA = __shfl_xor(wA, 32);
            if (!isK) {
                den += wA;
                acc.x += wA*(float)a01[0]; acc.y += wA*(float)a01[1];
                acc.z += wA*(float)a23[0]; acc.w += wA*(float)a23[1];
            }
        }
    }

    if (!isK) {
        float invd = 1.0f / den;
        float4* o = reinterpret_cast<float4*>(&outp[(size_t)node * FDIM + (lane - 32) * 4]);
        float4 cur = *o;
        cur.x += acc.x * invd;
        cur.y += acc.y * invd;
        cur.z += acc.z * invd;
        cur.w += acc.w * invd;
        *o = cur;
    }
}

// ---------------------------------------------------------------------------
extern "C" void kernel_launch(void* const* d_in, const int* in_sizes, int n_in,
                              void* d_out, int out_size, void* d_ws, size_t ws_size,
                              hipStream_t stream) {
    const float* x   = (const float*)d_in[0];
    const int*   ei  = (const int*)  d_in[1];
    const float* Wq  = (const float*)d_in[2];
    const float* bq  = (const float*)d_in[3];
    const float* Wk  = (const float*)d_in[4];
    const float* bk  = (const float*)d_in[5];
    const float* Wv  = (const float*)d_in[6];
    const float* bv  = (const float*)d_in[7];
    const float* Wsk = (const float*)d_in[8];
    const float* bsk = (const float*)d_in[9];
    float* outp = (float*)d_out;

    unsigned short* qb  = (unsigned short*)d_ws;                    // N*128 f16 (12.8MB)
    unsigned short* kv  = qb + (size_t)NNODES * FDIM;               // N*256 f16 (25.6MB)
    unsigned short* xa  = kv + (size_t)NNODES * 256;                // NT16*2048 bf16 (12.8MB)
    unsigned short* Wt2 = xa + (size_t)NT16 * 2048;                 // 128KB
    int* deg    = (int*)(Wt2 + 4 * FDIM * FDIM);
    int* rowptr = deg + NNODES;            // N+1
    int* ofs    = rowptr + NNODES + 1;     // N
    int* csr    = ofs + NNODES;            // E
    int* bsum   = csr + NEDGES;            // 49

    // 1: weights -> fragment order; zero deg
    tgd_prep<<<32 + NSCANB, 256, 0, stream>>>(Wq, Wk, Wv, Wsk, Wt2, deg);

    // 2: x -> xa (fragment-ordered bf16) + edge histogram tail
    tgd_cvt_xa<<<NT16, 256, 0, stream>>>(x, xa, ei, deg);

    // 3: GEMM
    tgd_gemm_mfma<<<NBLK, 512, 0, stream>>>(
        xa, Wt2, bq, bk, bv, bsk, qb, kv, outp);

    // 4-6: CSR build
    tgd_scan1<<<NSCANB, 1024, 0, stream>>>(deg, rowptr, bsum);
    tgd_scan3<<<NSCANB, 1024, 0, stream>>>(deg, bsum, rowptr, ofs);
    tgd_build<<<(NEDGES + 255) / 256, 256, 0, stream>>>(ei, ofs, csr);

    // 7: fused attention aggregation
    tgd_agg<<<(NNODES + 3) / 4, 256, 0, stream>>>(csr, rowptr, qb, kv, outp);
}